// Round 1
// baseline (57.633 us; speedup 1.0000x reference)
//
#include <hip/hip_runtime.h>
#include <math.h>

#define HIDDEN   100
#define NCLASS   4
#define MAXCHAIN 256
#define PAD      108   // LDS row stride (floats): 16B-aligned, b128 reads cover all 32 banks uniformly

// ---------------- ws layout ----------------
// byte 0   : int chain_len
// byte 8   : int warm_sink (DCE guard)
// byte 16  : int chain[MAXCHAIN]
// byte 16 + 4*MAXCHAIN : float a[MAXCHAIN][3][HIDDEN]   (W_m @ xe + b_m per chain node)

// K1: warm the tree region, then chase the ancestor chain of node (num_parent-1).
__global__ void k_chase(const int* __restrict__ tree, const int* __restrict__ np_ptr,
                        int* __restrict__ chain, int* __restrict__ chain_len,
                        int* __restrict__ warm_sink) {
    int npar = np_ptr[0];
    int K = npar - 1;
    if (K < 0) K = 0;
    // warm tree[0 .. 2*npar) into L1/L2 so the pointer chase hits cache
    int s = 0;
    for (int i = threadIdx.x; i < npar; i += blockDim.x) s += tree[2 * i];
    if (s == 0x7fffffff) *warm_sink = s;   // never true in practice; defeats DCE
    __syncthreads();
    if (threadIdx.x == 0) {
        int len = 0;
        int i = K;
        while (i > 0 && len < MAXCHAIN - 1) {
            chain[len++] = i;
            i = tree[2 * i];          // parent
        }
        chain[len++] = i;             // node 0 (parent_h = zeros)
        *chain_len = len;
    }
}

// K2: for each chain node, compute xe = E[:,idx]@val, then a_m = W_m@xe + b_m (m = z,r,h)
__global__ void k_prep(const float* __restrict__ xvals, const int* __restrict__ xidx,
                       const float* __restrict__ E, int vocab, int nwords,
                       const float* __restrict__ Wz, const float* __restrict__ bz,
                       const float* __restrict__ Wr, const float* __restrict__ br,
                       const float* __restrict__ Wh, const float* __restrict__ bh,
                       const int* __restrict__ chain, const int* __restrict__ chain_len_p,
                       float* __restrict__ a) {
    int L = *chain_len_p;
    __shared__ float xe[HIDDEN];
    int t = threadIdx.x;
    for (int d = blockIdx.x; d < L; d += gridDim.x) {
        int c = chain[d];
        if (t < HIDDEN) {
            float acc = 0.f;
            const float* Erow = E + (size_t)t * (size_t)vocab;
            const float* v = xvals + (size_t)c * nwords;
            const int*   ix = xidx + (size_t)c * nwords;
            #pragma unroll 4
            for (int w = 0; w < nwords; ++w)
                acc += v[w] * Erow[ix[w]];
            xe[t] = acc;
        }
        __syncthreads();
        for (int r = t; r < 3 * HIDDEN; r += blockDim.x) {
            int m = r / HIDDEN, i = r - m * HIDDEN;
            const float* Wm = (m == 0 ? Wz : (m == 1 ? Wr : Wh));
            const float* bm = (m == 0 ? bz : (m == 1 ? br : bh));
            float acc = bm[i];
            const float4* row = (const float4*)(Wm + i * HIDDEN);
            const float4* xv4 = (const float4*)xe;
            #pragma unroll
            for (int k = 0; k < HIDDEN / 4; ++k) {
                float4 wv = row[k];
                float4 xv = xv4[k];
                acc += wv.x * xv.x + wv.y * xv.y + wv.z * xv.z + wv.w * xv.w;
            }
            a[(d * 3 + m) * HIDDEN + i] = acc;
        }
        __syncthreads();
    }
}

// K3: sequential GRU recurrence over the chain (root-first), U matrices in LDS.
__global__ __launch_bounds__(256) void k_gru(
        const float* __restrict__ Uz, const float* __restrict__ Ur,
        const float* __restrict__ Uh,
        const float* __restrict__ Wout, const float* __restrict__ bout,
        const int* __restrict__ chain_len_p, const float* __restrict__ a,
        float* __restrict__ out) {
    extern __shared__ float smem[];
    float* U  = smem;                         // [3][HIDDEN][PAD]
    float* h0 = U + 3 * HIDDEN * PAD;         // 112 floats each, 16B aligned
    float* h1 = h0 + 112;
    float* zb = h1 + 112;
    float* rh = zb + 112;
    float* ov = rh + 112;                     // NCLASS partials

    int t = threadIdx.x;
    // stage U_z, U_r, U_h into LDS with padded rows
    for (int m = 0; m < 3; ++m) {
        const float* src = (m == 0 ? Uz : (m == 1 ? Ur : Uh));
        for (int idx = t; idx < HIDDEN * HIDDEN; idx += blockDim.x) {
            int i = idx / HIDDEN, j = idx - i * HIDDEN;
            U[(m * HIDDEN + i) * PAD + j] = src[idx];
        }
    }
    if (t < 112) { h0[t] = 0.f; h1[t] = 0.f; }
    __syncthreads();

    int L = *chain_len_p;
    float* hcur = h0;
    float* hnxt = h1;
    for (int d = L - 1; d >= 0; --d) {
        const float* ad = a + d * 3 * HIDDEN;
        if (t < 2 * HIDDEN) {                 // z and r matvecs
            int m = t / HIDDEN, i = t - m * HIDDEN;
            const float4* urow = (const float4*)(U + (m * HIDDEN + i) * PAD);
            const float4* hv4  = (const float4*)hcur;
            float acc = ad[m * HIDDEN + i];
            #pragma unroll
            for (int k = 0; k < HIDDEN / 4; ++k) {
                float4 u = urow[k];
                float4 hv = hv4[k];
                acc += u.x * hv.x + u.y * hv.y + u.z * hv.z + u.w * hv.w;
            }
            acc = fminf(fmaxf(acc, 0.f), 1.f);          // Hardtanh(0,1)
            if (m == 0) zb[i] = acc;                    // z
            else        rh[i] = acc * hcur[i];          // r * parent_h
        }
        __syncthreads();
        if (t < HIDDEN) {                     // c matvec + state update
            const float4* urow = (const float4*)(U + (2 * HIDDEN + t) * PAD);
            const float4* rv4  = (const float4*)rh;
            float acc = ad[2 * HIDDEN + t];
            #pragma unroll
            for (int k = 0; k < HIDDEN / 4; ++k) {
                float4 u = urow[k];
                float4 rv = rv4[k];
                acc += u.x * rv.x + u.y * rv.y + u.z * rv.z + u.w * rv.w;
            }
            float c = tanhf(acc);
            float z = zb[t];
            hnxt[t] = (1.f - z) * hcur[t] + z * c;
        }
        __syncthreads();
        float* tmp = hcur; hcur = hnxt; hnxt = tmp;
    }

    // out = softmax(W_out @ h + b_out)
    if (t < NCLASS) {
        float acc = bout[t];
        const float* row = Wout + t * HIDDEN;
        for (int j = 0; j < HIDDEN; ++j) acc += row[j] * hcur[j];
        ov[t] = acc;
    }
    __syncthreads();
    if (t == 0) {
        float mx = ov[0];
        for (int i = 1; i < NCLASS; ++i) mx = fmaxf(mx, ov[i]);
        float e[NCLASS], s = 0.f;
        for (int i = 0; i < NCLASS; ++i) { e[i] = expf(ov[i] - mx); s += e[i]; }
        for (int i = 0; i < NCLASS; ++i) out[i] = e[i] / s;
    }
}

extern "C" void kernel_launch(void* const* d_in, const int* in_sizes, int n_in,
                              void* d_out, int out_size, void* d_ws, size_t ws_size,
                              hipStream_t stream) {
    const float* xvals = (const float*)d_in[0];
    const int*   xidx  = (const int*)d_in[1];
    const int*   tree  = (const int*)d_in[2];
    const int*   npar  = (const int*)d_in[3];
    const float* E     = (const float*)d_in[4];
    const float* Wz    = (const float*)d_in[5];
    const float* Uz    = (const float*)d_in[6];
    const float* bz    = (const float*)d_in[7];
    const float* Wr    = (const float*)d_in[8];
    const float* Ur    = (const float*)d_in[9];
    const float* br    = (const float*)d_in[10];
    const float* Wh    = (const float*)d_in[11];
    const float* Uh    = (const float*)d_in[12];
    const float* bh    = (const float*)d_in[13];
    const float* Wout  = (const float*)d_in[14];
    const float* bout  = (const float*)d_in[15];

    int n_edges = in_sizes[2] / 2;
    int nwords  = in_sizes[0] / n_edges;      // 40
    int vocab   = in_sizes[4] / HIDDEN;       // 50000

    int*   chain_len = (int*)d_ws;
    int*   sink      = (int*)d_ws + 2;
    int*   chain     = (int*)((char*)d_ws + 16);
    float* a         = (float*)((char*)d_ws + 16 + 4 * MAXCHAIN);

    k_chase<<<1, 256, 0, stream>>>(tree, npar, chain, chain_len, sink);
    k_prep<<<32, 128, 0, stream>>>(xvals, xidx, E, vocab, nwords,
                                   Wz, bz, Wr, br, Wh, bh,
                                   chain, chain_len, a);
    size_t smem_bytes = (3 * HIDDEN * PAD + 4 * 112 + 16) * sizeof(float);
    // allow >64KB dynamic LDS (no-op if already permitted)
    static bool attr_set = false;
    if (!attr_set) {
        hipFuncSetAttribute((const void*)k_gru,
                            hipFuncAttributeMaxDynamicSharedMemorySize,
                            (int)smem_bytes);
        attr_set = true;
    }
    k_gru<<<1, 256, smem_bytes, stream>>>(Uz, Ur, Uh, Wout, bout,
                                          chain_len, a, (float*)d_out);
}

// Round 2
// 43.873 us; speedup vs baseline: 1.3137x; 1.3137x over previous
//
#include <hip/hip_runtime.h>
#include <math.h>

#define HIDDEN   100
#define NCLASS   4
#define MAXCHAIN 256
#define PAD      108     // LDS row stride in floats (432B, 16B-aligned)
#define NWORDS   40
#define VOCAB    50000

// ---------------- ws layout ----------------
// byte 0  : int chain_len
// byte 8  : int sink_i
// byte 12 : float sink_f
// byte 16 : int chain[MAXCHAIN]            (unused by K3, kept for debug)
// byte 16+4*MAXCHAIN : float a[MAXCHAIN][3][HIDDEN]

// K1: warm tree, chase chain, gather xe per chain node, compute a_m = W_m@xe + b_m.
// Upper blocks additionally warm U_z/U_r/U_h/W_out into L2 for K2.
__global__ __launch_bounds__(512) void k_prep2(
        const float* __restrict__ xvals, const int* __restrict__ xidx,
        const int* __restrict__ tree, const int* __restrict__ np_ptr,
        const float* __restrict__ E,
        const float* __restrict__ Wz, const float* __restrict__ bz,
        const float* __restrict__ Wr, const float* __restrict__ br,
        const float* __restrict__ Wh, const float* __restrict__ bh,
        const float* __restrict__ Uz, const float* __restrict__ Ur,
        const float* __restrict__ Uh, const float* __restrict__ Wout,
        int* __restrict__ chain_len_out, int* __restrict__ chain_out,
        float* __restrict__ a, int* __restrict__ sink_i, float* __restrict__ sink_f) {
    __shared__ int chain_s[MAXCHAIN];
    __shared__ int len_s;
    __shared__ __align__(16) float xep[4 * HIDDEN];
    __shared__ __align__(16) float xe[HIDDEN];
    int t = threadIdx.x;
    int bid = blockIdx.x;
    int npar = np_ptr[0];

    // warm tree region so the chase hits cache (independent coalesced loads)
    int si = 0;
    for (int i = t; i < 2 * npar; i += 512) si += tree[i];
    // upper blocks: warm U matrices + W_out into L2 for k_gru2
    float sf = 0.f;
    if (bid >= 16) {
        for (int i = (bid - 16) * 512 + t; i < HIDDEN * HIDDEN; i += 16 * 512)
            sf += Uz[i] + Ur[i] + Uh[i];
        int o = (bid - 16) * 512 + t;
        if (o < NCLASS * HIDDEN) sf += Wout[o];
    }
    if (si == 0x7fffffff) *sink_i = si;     // never true; defeats DCE
    if (sf > 1e30f) *sink_f = sf;           // never true; defeats DCE
    __syncthreads();

    if (t == 0) {
        int len = 0, i = npar - 1;
        if (i < 0) i = 0;
        while (i > 0 && len < MAXCHAIN - 1) { chain_s[len++] = i; i = tree[2 * i]; }
        chain_s[len++] = i;                  // node 0 (zero parent state)
        len_s = len;
        if (bid == 0) {
            *chain_len_out = len;
            for (int k = 0; k < len; ++k) chain_out[k] = chain_s[k];
        }
    }
    __syncthreads();
    int L = len_s;

    for (int d = bid; d < L; d += gridDim.x) {
        int c = chain_s[d];
        // gather xe[h] = sum_w val[w] * E[h, idx[w]]  (4 word-groups x 100 hidden)
        if (t < 4 * HIDDEN) {
            int h = t >> 2, wg = t & 3;
            const int*   ixp = xidx  + (size_t)c * NWORDS + wg * (NWORDS / 4);
            const float* vp  = xvals + (size_t)c * NWORDS + wg * (NWORDS / 4);
            int   ix[NWORDS / 4];
            float vv[NWORDS / 4];
            #pragma unroll
            for (int w = 0; w < NWORDS / 4; ++w) ix[w] = ixp[w];
            #pragma unroll
            for (int w = 0; w < NWORDS / 4; ++w) vv[w] = vp[w];
            const float* Eh = E + (size_t)h * VOCAB;
            float acc = 0.f;
            #pragma unroll
            for (int w = 0; w < NWORDS / 4; ++w) acc += vv[w] * Eh[ix[w]];
            xep[t] = acc;                    // t == h*4 + wg
        }
        __syncthreads();
        if (t < HIDDEN) {
            float4 p = ((const float4*)xep)[t];
            xe[t] = p.x + p.y + p.z + p.w;
        }
        __syncthreads();
        // a_m = W_m @ xe + b_m   (300 rows in parallel)
        if (t < 3 * HIDDEN) {
            int m = t / HIDDEN, i = t - m * HIDDEN;
            const float* Wm = (m == 0 ? Wz : (m == 1 ? Wr : Wh));
            const float* bm = (m == 0 ? bz : (m == 1 ? br : bh));
            const float4* row = (const float4*)(Wm + i * HIDDEN);
            const float4* x4  = (const float4*)xe;
            float acc = bm[i];
            #pragma unroll
            for (int k = 0; k < HIDDEN / 4; ++k) {
                float4 w = row[k], x = x4[k];
                acc += w.x * x.x + w.y * x.y + w.z * x.z + w.w * x.w;
            }
            a[(d * 3 + m) * HIDDEN + i] = acc;
        }
        __syncthreads();
    }
}

// K2: sequential GRU recurrence over the chain, U in LDS (ILP-batched staging).
__global__ __launch_bounds__(512) void k_gru2(
        const float* __restrict__ Uz, const float* __restrict__ Ur,
        const float* __restrict__ Uh,
        const float* __restrict__ Wout, const float* __restrict__ bout,
        const int* __restrict__ chain_len_p, const float* __restrict__ a,
        float* __restrict__ out) {
    extern __shared__ float smem[];
    float* U  = smem;                        // [3][HIDDEN][PAD]
    float* h0 = U + 3 * HIDDEN * PAD;        // 112 floats each, 16B aligned
    float* h1 = h0 + 112;
    float* zb = h1 + 112;
    float* rh = zb + 112;
    float* ov = rh + 112;
    int t = threadIdx.x;

    // stage U: per matrix, 2500 float4 -> 5 independent loads/thread, then 5 writes
    #pragma unroll
    for (int m = 0; m < 3; ++m) {
        const float4* src = (const float4*)(m == 0 ? Uz : (m == 1 ? Ur : Uh));
        float4 r[5];
        #pragma unroll
        for (int j = 0; j < 5; ++j) {
            int k = t + j * 512;
            if (k < 2500) r[j] = src[k];
        }
        #pragma unroll
        for (int j = 0; j < 5; ++j) {
            int k = t + j * 512;
            if (k < 2500) {
                int row = k / 25, c4 = k - row * 25;
                *(float4*)(U + (m * HIDDEN + row) * PAD + c4 * 4) = r[j];
            }
        }
    }
    if (t < 112) { h0[t] = 0.f; h1[t] = 0.f; }
    __syncthreads();

    int L = *chain_len_p;
    float* hc = h0;
    float* hn = h1;
    for (int d = L - 1; d >= 0; --d) {
        const float* ad = a + d * 3 * HIDDEN;
        if (t < 2 * HIDDEN) {                // z and r rows
            int m = t / HIDDEN, i = t - m * HIDDEN;
            const float4* ur = (const float4*)(U + (m * HIDDEN + i) * PAD);
            const float4* h4 = (const float4*)hc;
            float acc = ad[m * HIDDEN + i];
            #pragma unroll
            for (int k = 0; k < HIDDEN / 4; ++k) {
                float4 u = ur[k], h = h4[k];
                acc += u.x * h.x + u.y * h.y + u.z * h.z + u.w * h.w;
            }
            acc = fminf(fmaxf(acc, 0.f), 1.f);          // Hardtanh(0,1)
            if (m == 0) zb[i] = acc;                    // z
            else        rh[i] = acc * hc[i];            // r * parent_h
        }
        __syncthreads();
        if (t < HIDDEN) {                    // c row + state update
            const float4* ur = (const float4*)(U + (2 * HIDDEN + t) * PAD);
            const float4* r4 = (const float4*)rh;
            float acc = ad[2 * HIDDEN + t];
            #pragma unroll
            for (int k = 0; k < HIDDEN / 4; ++k) {
                float4 u = ur[k], h = r4[k];
                acc += u.x * h.x + u.y * h.y + u.z * h.z + u.w * h.w;
            }
            float c = tanhf(acc);
            float z = zb[t];
            hn[t] = (1.f - z) * hc[t] + z * c;
        }
        __syncthreads();
        float* tmp = hc; hc = hn; hn = tmp;
    }

    if (t < NCLASS) {
        float acc = bout[t];
        const float* row = Wout + t * HIDDEN;
        for (int j = 0; j < HIDDEN; ++j) acc += row[j] * hc[j];
        ov[t] = acc;
    }
    __syncthreads();
    if (t == 0) {
        float mx = fmaxf(fmaxf(ov[0], ov[1]), fmaxf(ov[2], ov[3]));
        float e0 = expf(ov[0] - mx), e1 = expf(ov[1] - mx);
        float e2 = expf(ov[2] - mx), e3 = expf(ov[3] - mx);
        float s = e0 + e1 + e2 + e3;
        out[0] = e0 / s; out[1] = e1 / s; out[2] = e2 / s; out[3] = e3 / s;
    }
}

extern "C" void kernel_launch(void* const* d_in, const int* in_sizes, int n_in,
                              void* d_out, int out_size, void* d_ws, size_t ws_size,
                              hipStream_t stream) {
    const float* xvals = (const float*)d_in[0];
    const int*   xidx  = (const int*)d_in[1];
    const int*   tree  = (const int*)d_in[2];
    const int*   npar  = (const int*)d_in[3];
    const float* E     = (const float*)d_in[4];
    const float* Wz    = (const float*)d_in[5];
    const float* Uz    = (const float*)d_in[6];
    const float* bz    = (const float*)d_in[7];
    const float* Wr    = (const float*)d_in[8];
    const float* Ur    = (const float*)d_in[9];
    const float* br    = (const float*)d_in[10];
    const float* Wh    = (const float*)d_in[11];
    const float* Uh    = (const float*)d_in[12];
    const float* bh    = (const float*)d_in[13];
    const float* Wout  = (const float*)d_in[14];
    const float* bout  = (const float*)d_in[15];

    int*   chain_len = (int*)d_ws;
    int*   sink_i    = (int*)d_ws + 2;
    float* sink_f    = (float*)d_ws + 3;
    int*   chain     = (int*)((char*)d_ws + 16);
    float* a         = (float*)((char*)d_ws + 16 + 4 * MAXCHAIN);

    k_prep2<<<32, 512, 0, stream>>>(xvals, xidx, tree, npar, E,
                                    Wz, bz, Wr, br, Wh, bh,
                                    Uz, Ur, Uh, Wout,
                                    chain_len, chain, a, sink_i, sink_f);

    size_t smem_bytes = (3 * HIDDEN * PAD + 4 * 112 + 8) * sizeof(float);
    static bool attr_set = false;
    if (!attr_set) {
        hipFuncSetAttribute((const void*)k_gru2,
                            hipFuncAttributeMaxDynamicSharedMemorySize,
                            (int)smem_bytes);
        attr_set = true;
    }
    k_gru2<<<1, 512, smem_bytes, stream>>>(Uz, Ur, Uh, Wout, bout,
                                           chain_len, a, (float*)d_out);
}